// Round 9
// baseline (98.793 us; speedup 1.0000x reference)
//
#include <hip/hip_runtime.h>

// QuantizedLinear: out[t][o] = sum_k x[t][k] * (w_q[o][k]-128)*scale[o] + bias[o]
// M=16, N=8192, K=8192. Memory-bound on w_q (256 MB int32, read once).
//
// R9: R6 barrier-free stream + explicit DEPTH-4 w-prefetch. Theory: R6
// (75.7us, 3.5 TB/s) was latency-limited -- ~6.3 TB/s needs ~9 KB/CU in
// flight (900cy x 10.25 B/cy); R6 held ~2 k-steps and every x-wait (in-order
// vmcnt) drained the w-pipe. Here 4 statically-named int4[4] buffers keep
// 12-16 KB/wave of w in flight; w and x are addressed as wave-uniform
// SGPR base + one shared lane offset (koff) so per-step VALU addr math ~1 op.
// R8's split-K (91.6us) showed prologue/epilogue must stay amortized over
// full K: monolithic, no LDS, no barriers, one epilogue.

#define IN_F   8192
#define OUT_F  8192
#define NT     16
#define BLOCK  256
#define W_O    4
#define CH_PER_BLOCK 16    // 4 waves * W_O
#define NSTEP  (IN_F / 256)  // 32

__global__ __launch_bounds__(BLOCK, 2)
void qlin_kernel(const float* __restrict__ x,     // [16][8192]
                 const int*   __restrict__ w_q,   // [8192][8192]
                 const float* __restrict__ scale, // [8192]
                 const float* __restrict__ bias,  // [8192]
                 float* __restrict__ out)         // [16][8192]
{
    const int tid  = threadIdx.x;
    const int lane = tid & 63;
    const int wave = tid >> 6;
    const int o_base = blockIdx.x * CH_PER_BLOCK + wave * W_O;

    const int koff = lane * 4;   // element offset inside a 256-wide k-step

    // wave-uniform row bases -> SGPR; loads become s-base + v-offset
    const int* wrow[W_O];
#pragma unroll
    for (int j = 0; j < W_O; ++j)
        wrow[j] = w_q + (size_t)(o_base + j) * IN_F;

    float acc[NT][W_O];
#pragma unroll
    for (int t = 0; t < NT; ++t)
#pragma unroll
        for (int j = 0; j < W_O; ++j) acc[t][j] = 0.0f;

    int4 b0[W_O], b1[W_O], b2[W_O], b3[W_O];   // depth-4 rotating w buffers

#define LOADW(B, ks)                                                  \
    {                                                                 \
        _Pragma("unroll")                                             \
        for (int j = 0; j < W_O; ++j)                                 \
            B[j] = *reinterpret_cast<const int4*>(                    \
                wrow[j] + (ks) * 256 + koff);                         \
    }

#define STEP(B, ks)                                                   \
    {                                                                 \
        float wf[W_O][4];                                             \
        _Pragma("unroll")                                             \
        for (int j = 0; j < W_O; ++j) {                               \
            wf[j][0] = (float)(B[j].x - 128);                         \
            wf[j][1] = (float)(B[j].y - 128);                         \
            wf[j][2] = (float)(B[j].z - 128);                         \
            wf[j][3] = (float)(B[j].w - 128);                         \
        }                                                             \
        _Pragma("unroll")                                             \
        for (int t = 0; t < NT; ++t) {                                \
            const float4 xv = *reinterpret_cast<const float4*>(       \
                x + (size_t)t * IN_F + (ks) * 256 + koff);            \
            _Pragma("unroll")                                         \
            for (int j = 0; j < W_O; ++j) {                           \
                acc[t][j] += wf[j][0] * xv.x;                         \
                acc[t][j] += wf[j][1] * xv.y;                         \
                acc[t][j] += wf[j][2] * xv.z;                         \
                acc[t][j] += wf[j][3] * xv.w;                         \
            }                                                         \
        }                                                             \
    }

    LOADW(b0, 0) LOADW(b1, 1) LOADW(b2, 2) LOADW(b3, 3)

#pragma unroll 1
    for (int g = 0; g < (NSTEP / 4) - 1; ++g) {   // 7 groups
        const int i = g * 4;
        STEP(b0, i + 0) LOADW(b0, i + 4)
        STEP(b1, i + 1) LOADW(b1, i + 5)
        STEP(b2, i + 2) LOADW(b2, i + 6)
        STEP(b3, i + 3) LOADW(b3, i + 7)
    }
    STEP(b0, NSTEP - 4)
    STEP(b1, NSTEP - 3)
    STEP(b2, NSTEP - 2)
    STEP(b3, NSTEP - 1)

#undef LOADW
#undef STEP

    // ---- cross-lane reduction: 64 (t,j) values, 6-step butterfly each ----
    float myval = 0.0f;
#pragma unroll
    for (int t = 0; t < NT; ++t) {
#pragma unroll
        for (int j = 0; j < W_O; ++j) {
            float v = acc[t][j];
#pragma unroll
            for (int off = 32; off > 0; off >>= 1)
                v += __shfl_xor(v, off, 64);
            if (lane == (t * W_O + j)) myval = v;
        }
    }

    // lane l -> (t = l>>2, channel j = l&3)
    const int t_o = lane >> 2;
    const int o   = o_base + (lane & 3);
    out[(size_t)t_o * OUT_F + o] = myval * scale[o] + bias[o];
}

extern "C" void kernel_launch(void* const* d_in, const int* in_sizes, int n_in,
                              void* d_out, int out_size, void* d_ws, size_t ws_size,
                              hipStream_t stream) {
    const float* x     = (const float*)d_in[0];
    const int*   w_q   = (const int*)d_in[1];
    const float* scale = (const float*)d_in[2];
    const float* bias  = (const float*)d_in[3];
    float*       out   = (float*)d_out;

    dim3 grid(OUT_F / CH_PER_BLOCK);   // 512 blocks -> 2 per CU
    dim3 block(BLOCK);
    qlin_kernel<<<grid, block, 0, stream>>>(x, w_q, scale, bias, out);
}